// Round 19
// baseline (146.449 us; speedup 1.0000x reference)
//
#include <hip/hip_runtime.h>
#include <math.h>

#define Nn 4096
#define Ee 384
#define Hh 6
#define DHh 64
#define MIDm 96
#define TEe 1152
#define SPLIT 8

typedef short s16x8 __attribute__((ext_vector_type(8)));
typedef float f32x4 __attribute__((ext_vector_type(4)));
typedef float f32x16 __attribute__((ext_vector_type(16)));
typedef unsigned short ushort_t;
typedef unsigned short ushort4_t __attribute__((ext_vector_type(4)));

#define CROW(r, hf) ((((r) & 3)) + 8 * ((r) >> 2) + 4 * (hf))

__device__ __forceinline__ float gelu_exact(float x) {
    return 0.5f * x * (1.0f + erff(x * 0.70710678118654752f));
}
__device__ __forceinline__ float sigmoidf_(float x) {
    return 1.0f / (1.0f + __expf(-x));
}
__device__ __forceinline__ ushort_t f2bf(float x) {
    unsigned int u = __float_as_uint(x);
    u = (u + 0x7FFFu + ((u >> 16) & 1u)) >> 16;
    return (ushort_t)u;
}
__device__ __forceinline__ float bf2f(ushort_t u) {
    return __uint_as_float(((unsigned int)u) << 16);
}
__device__ __forceinline__ unsigned int cvtpk(float a, float b) {
    unsigned int r;
    asm("v_cvt_pk_bf16_f32 %0, %1, %2" : "=v"(r) : "v"(a), "v"(b));
    return r;
}
// async global->LDS 16B: per-lane global src, wave-uniform LDS base + lane*16
__device__ __forceinline__ void gld16(const ushort_t* g, ushort_t* l) {
    __builtin_amdgcn_global_load_lds(
        (const __attribute__((address_space(1))) unsigned int*)g,
        (__attribute__((address_space(3))) unsigned int*)l, 16, 0, 0);
}

// weight-region offsets (ushort units)
#define W1L_OFF 0
#define W1H_OFF 36864
#define W2L_OFF 73728
#define W2H_OFF 110592
#define WQKV_OFF 147456
#define WO_OFF 589824

// ---------------- kernel: tiled transpose+convert weights to bf16 ----------------
__global__ __launch_bounds__(256) void k_cvt(
    const float* __restrict__ lw1, const float* __restrict__ hw1,
    const float* __restrict__ lw2, const float* __restrict__ hw2,
    const float* __restrict__ wqkv, const float* __restrict__ wo,
    ushort_t* __restrict__ wT) {
    __shared__ float tl[32][33];
    const int b = blockIdx.x;
    const float* src;
    int R, C, doff, ti;
    if (b < 36)       { src = lw1;  R = 384; C = 96;   doff = W1L_OFF;  ti = b; }
    else if (b < 72)  { src = hw1;  R = 384; C = 96;   doff = W1H_OFF;  ti = b - 36; }
    else if (b < 108) { src = lw2;  R = 96;  C = 384;  doff = W2L_OFF;  ti = b - 72; }
    else if (b < 144) { src = hw2;  R = 96;  C = 384;  doff = W2H_OFF;  ti = b - 108; }
    else if (b < 576) { src = wqkv; R = 384; C = 1152; doff = WQKV_OFF; ti = b - 144; }
    else              { src = wo;   R = 384; C = 384;  doff = WO_OFF;   ti = b - 576; }
    const int tcn = C >> 5;
    const int tr = ti / tcn, tc = ti % tcn;
    const int col = threadIdx.x & 31, r8 = threadIdx.x >> 5;
#pragma unroll
    for (int i = 0; i < 4; i++) {
        const int row = r8 + 8 * i;
        tl[row][col] = src[(size_t)(tr * 32 + row) * C + tc * 32 + col];
    }
    __syncthreads();
#pragma unroll
    for (int i = 0; i < 4; i++) {
        const int rowp = r8 + 8 * i;  // src-col within tile
        wT[doff + (size_t)(tc * 32 + rowp) * R + tr * 32 + col] = f2bf(tl[col][rowp]);
    }
}

// ---------------- kernel: dual channel-MLP + layer fuse (16x16x32 MFMA) ----------------
// grid 256 x 256 thr (4 waves = stream x n-half); 16 rows/block
__global__ __launch_bounds__(256) void k_mlp(
    const float* __restrict__ low, const float* __restrict__ high,
    const float* __restrict__ lf, const ushort_t* __restrict__ wT,
    const float* __restrict__ lb1, const float* __restrict__ lb2,
    const float* __restrict__ hb1, const float* __restrict__ hb2,
    ushort_t* __restrict__ fusedb) {
    __shared__ ushort_t Hs[2][16][104];
    __shared__ ushort_t Sg[2][16][384];
    const int t = threadIdx.x;
    const int w = t >> 6, l = t & 63, l15 = l & 15, g4 = l >> 4;
    const int st = w >> 1, nh = w & 1;
    const int rb = blockIdx.x * 16;
    const float* Xf = st ? high : low;
    const ushort_t* w1T = wT + (st ? W1H_OFF : W1L_OFF);
    const ushort_t* w2T = wT + (st ? W2H_OFF : W2L_OFF);
    const float* b1p = st ? hb1 : lb1;
    const float* b2p = st ? hb2 : lb2;
    // ---- GEMM1: wave (st, nh) computes cols nh*48..+48, full K=384
    {
        f32x4 hA[3];
#pragma unroll
        for (int nt = 0; nt < 3; nt++) hA[nt] = (f32x4){0.f, 0.f, 0.f, 0.f};
        for (int ks = 0; ks < 12; ks++) {
            const float* ap = &Xf[(size_t)(rb + l15) * 384 + ks * 32 + g4 * 8];
            f32x4 a0 = *(const f32x4*)ap;
            f32x4 a1 = *(const f32x4*)(ap + 4);
            union { unsigned int uw[4]; s16x8 v; } ua;
            ua.uw[0] = cvtpk(a0[0], a0[1]);
            ua.uw[1] = cvtpk(a0[2], a0[3]);
            ua.uw[2] = cvtpk(a1[0], a1[1]);
            ua.uw[3] = cvtpk(a1[2], a1[3]);
#pragma unroll
            for (int nt = 0; nt < 3; nt++) {
                s16x8 bf = *(const s16x8*)&w1T[(nh * 48 + nt * 16 + l15) * 384 + ks * 32 + g4 * 8];
                hA[nt] = __builtin_amdgcn_mfma_f32_16x16x32_bf16(ua.v, bf, hA[nt], 0, 0, 0);
            }
        }
#pragma unroll
        for (int nt = 0; nt < 3; nt++) {
            const int mc = nh * 48 + nt * 16 + l15;
            const float bb = b1p[mc];
#pragma unroll
            for (int r = 0; r < 4; r++)
                Hs[st][g4 * 4 + r][mc] = f2bf(gelu_exact(hA[nt][r] + bb));
        }
    }
    __syncthreads();
    // ---- GEMM2: wave (st, nh) covers 192 cols: 12 chains x 3 ksteps
    {
        f32x4 sA[12];
#pragma unroll
        for (int nt = 0; nt < 12; nt++) sA[nt] = (f32x4){0.f, 0.f, 0.f, 0.f};
#pragma unroll
        for (int ks = 0; ks < 3; ks++) {
            s16x8 af = *(const s16x8*)&Hs[st][l15][ks * 32 + g4 * 8];
#pragma unroll
            for (int nt = 0; nt < 12; nt++) {
                s16x8 bf = *(const s16x8*)&w2T[(nh * 192 + nt * 16 + l15) * 96 + ks * 32 + g4 * 8];
                sA[nt] = __builtin_amdgcn_mfma_f32_16x16x32_bf16(af, bf, sA[nt], 0, 0, 0);
            }
        }
#pragma unroll
        for (int nt = 0; nt < 12; nt++) {
            const float bb = b2p[nh * 192 + nt * 16 + l15];
#pragma unroll
            for (int r = 0; r < 4; r++)
                Sg[st][g4 * 4 + r][nh * 192 + nt * 16 + l15] = f2bf(sigmoidf_(sA[nt][r] + bb));
        }
    }
    __syncthreads();
    // ---- fuse epilogue
    {
        const float a0 = lf[0], a1 = lf[1];
        const float mx = fmaxf(a0, a1);
        const float e0 = __expf(a0 - mx), e1 = __expf(a1 - mx);
        const float inv = 1.0f / (e0 + e1);
        const float w0 = e0 * inv, w1v = e1 * inv;
        for (int base = t * 4; base < 16 * 384; base += 256 * 4) {
            const int row = base / 384, e0i = base % 384;
            const int gr = rb + row;
            f32x4 lo4 = *(const f32x4*)&low[(size_t)gr * 384 + e0i];
            f32x4 hi4 = *(const f32x4*)&high[(size_t)gr * 384 + e0i];
            ushort4_t s0 = *(const ushort4_t*)&Sg[0][row][e0i];
            ushort4_t s1 = *(const ushort4_t*)&Sg[1][row][e0i];
            ushort4_t fb;
#pragma unroll
            for (int i = 0; i < 4; i++)
                fb[i] = f2bf(w0 * lo4[i] * bf2f(s0[i]) + w1v * hi4[i] * bf2f(s1[i]));
            *(ushort4_t*)&fusedb[(size_t)gr * 384 + e0i] = fb;
        }
    }
}

// ---------------- kernel: qkv projection (32x32x16 MFMA, no A-staging) ----------------
// grid (128, 6) x 128 thr (2 waves); 32 rows x 192 cols per block
__global__ __launch_bounds__(128) void k_qkv(
    const ushort_t* __restrict__ fusedb, const ushort_t* __restrict__ wT,
    const float* __restrict__ bqkv,
    ushort_t* __restrict__ qb, ushort_t* __restrict__ kb, ushort_t* __restrict__ vtb) {
    __shared__ float tls[2][32][40];
    const int t = threadIdx.x;
    const int w = t >> 6, l = t & 63, ll = l & 31, hf = l >> 5;
    const int rb = blockIdx.x * 32;
    const int cb = blockIdx.y * 192 + w * 96;
    const ushort_t* wq = wT + WQKV_OFF;
    f32x16 acc[3];
#pragma unroll
    for (int nt = 0; nt < 3; nt++)
#pragma unroll
        for (int r = 0; r < 16; r++) acc[nt][r] = 0.0f;
    for (int ks = 0; ks < 24; ks++) {
        s16x8 af = *(const s16x8*)&fusedb[(size_t)(rb + ll) * 384 + ks * 16 + hf * 8];
#pragma unroll
        for (int nt = 0; nt < 3; nt++) {
            s16x8 bf = *(const s16x8*)&wq[(size_t)(cb + nt * 32 + ll) * 384 + ks * 16 + hf * 8];
            acc[nt] = __builtin_amdgcn_mfma_f32_32x32x16_bf16(af, bf, acc[nt], 0, 0, 0);
        }
    }
#pragma unroll
    for (int nt = 0; nt < 3; nt++) {
        const int nb = cb + nt * 32;
        const int which = nb / 384, wn = nb % 384;
        const int hb = wn >> 6, d0 = wn & 63;
        const float bias = bqkv[nb + ll];
        if (which == 2) {
            const int d = d0 + ll;
#pragma unroll
            for (int g2 = 0; g2 < 4; g2++) {
                ushort4_t u4;
#pragma unroll
                for (int i2 = 0; i2 < 4; i2++) u4[i2] = f2bf(acc[nt][g2 * 4 + i2] + bias);
                *(ushort4_t*)&vtb[((size_t)(hb * 64 + d)) * Nn + rb + 8 * g2 + 4 * hf] = u4;
            }
        } else {
            const float sc = (which == 0) ? 0.18033688f : 1.0f;  // 0.125*log2(e) on q
#pragma unroll
            for (int r = 0; r < 16; r++) tls[w][CROW(r, hf)][ll] = (acc[nt][r] + bias) * sc;
            ushort_t* dst = which ? kb : qb;
            const int row2 = l >> 1, sg = l & 1;
            union { ushort_t us[16]; s16x8 v[2]; } u;
#pragma unroll
            for (int j = 0; j < 16; j++) u.us[j] = f2bf(tls[w][row2][sg * 16 + j]);
            size_t base = ((size_t)hb * Nn + rb + row2) * 64 + d0 + sg * 16;
            *(s16x8*)&dst[base] = u.v[0];
            *(s16x8*)&dst[base + 8] = u.v[1];
        }
    }
}

// ---------------- kernel: flash attention, softmax-free ----------------
// K fragments DIRECT from global (L1-broadcast across the 8 waves); V LDS-staged (3-buf, counted vmcnt)
// flat grid 768 (XCD-swizzled) x 512 thr (8 waves); KV tile 64
// pof layout: [sp][q/16][e][q%16]
__global__ __launch_bounds__(512) void k_attn(
    const ushort_t* __restrict__ qb, const ushort_t* __restrict__ kb,
    const ushort_t* __restrict__ vtb, ushort_t* __restrict__ pof,
    float* __restrict__ pml) {
    __shared__ ushort_t Vt[3][4096];
    const int t = threadIdx.x;
    const int wid8 = t >> 6, l = t & 63, ll = l & 31, hf = l >> 5;
    const int lid = blockIdx.x;
    const int xcd = lid & 7, gi = lid >> 3;
    const int pair = xcd * 6 + (gi >> 4);
    const int qt = gi & 15;
    const int h = pair % Hh, sp = pair / Hh;
    const int qrow0 = qt * 256 + wid8 * 32;
    const int srow = t >> 3;
    const int sslot = ((l & 7) ^ (l >> 3)) * 8;
    const int wch = wid8 * 512;
    const ushort_t* kbase = kb + (size_t)h * Nn * DHh;
    const ushort_t* vbase = vtb + (size_t)h * DHh * Nn;
    const int kst0 = sp * (Nn / SPLIT);
#define NT (Nn / (64 * SPLIT))
#define STAGE(B, TI) { const int ktb2 = kst0 + (TI) * 64;                                \
        gld16(vbase + (size_t)srow * Nn + ktb2 + sslot, &Vt[B][wch]); }

    s16x8 qf[4];
#pragma unroll
    for (int dc = 0; dc < 4; dc++)
        qf[dc] = *(const s16x8*)&qb[((size_t)h * Nn + qrow0 + ll) * DHh + dc * 16 + hf * 8];
    f32x16 zro;
#pragma unroll
    for (int r = 0; r < 16; r++) zro[r] = 0.0f;
    f32x16 o0 = zro, o1 = zro;
    float lsum = 0.0f;
    const int xorl = (ll & 7) << 3;
    // per-lane K fragment pointers (direct global; dc offsets fold to immediates)
    const ushort_t* pK0 = kbase + (size_t)(kst0 + ll) * DHh + hf * 8;
    const ushort_t* pK1 = pK0 + 32 * DHh;

    // 2-deep V-DMA pipeline prologue
    STAGE(0, 0);
    STAGE(1, 1);
    asm volatile("s_waitcnt vmcnt(1)" ::: "memory");   // tile 0's V landed
    __builtin_amdgcn_s_barrier();
    __builtin_amdgcn_sched_barrier(0);
    int cur = 0;
    for (int kt = 0; kt < NT; kt++) {
        int nb = cur + 2; if (nb >= 3) nb -= 3;
        if (kt + 2 < NT) STAGE(nb, kt + 2);            // keep 2 V tiles in flight
        const ushort_t* VtC = Vt[cur];
        __builtin_amdgcn_s_setprio(1);
        f32x16 s0, s1;
        {
            s16x8 kf0 = *(const s16x8*)(pK0);
            s16x8 kf1 = *(const s16x8*)(pK1);
            s0 = __builtin_amdgcn_mfma_f32_32x32x16_bf16(kf0, qf[0], zro, 0, 0, 0);
            s1 = __builtin_amdgcn_mfma_f32_32x32x16_bf16(kf1, qf[0], zro, 0, 0, 0);
        }
#pragma unroll
        for (int dc = 1; dc < 4; dc++) {
            s16x8 kf0 = *(const s16x8*)(pK0 + dc * 16);
            s16x8 kf1 = *(const s16x8*)(pK1 + dc * 16);
            s0 = __builtin_amdgcn_mfma_f32_32x32x16_bf16(kf0, qf[dc], s0, 0, 0, 0);
            s1 = __builtin_amdgcn_mfma_f32_32x32x16_bf16(kf1, qf[dc], s1, 0, 0, 0);
        }
        __builtin_amdgcn_s_setprio(0);
        pK0 += 64 * DHh;
        pK1 += 64 * DHh;
#pragma unroll
        for (int r = 0; r < 16; r++) { s0[r] = exp2f(s0[r]); lsum += s0[r]; }
#pragma unroll
        for (int r = 0; r < 16; r++) { s1[r] = exp2f(s1[r]); lsum += s1[r]; }
#pragma unroll
        for (int ks = 0; ks < 4; ks++) {
            const f32x16 S = (ks < 2) ? s0 : s1;
            const int b = (ks & 1) * 8;
            unsigned int t1 = cvtpk(S[b + 0], S[b + 1]);
            unsigned int t3 = cvtpk(S[b + 2], S[b + 3]);
            unsigned int t2 = cvtpk(S[b + 4], S[b + 5]);
            unsigned int t4 = cvtpk(S[b + 6], S[b + 7]);
            asm("v_permlane32_swap_b32 %0, %1" : "+v"(t1), "+v"(t2));
            asm("v_permlane32_swap_b32 %0, %1" : "+v"(t3), "+v"(t4));
            union { unsigned int uw[4]; s16x8 v; } u;
            u.uw[0] = t1;
            u.uw[1] = t3;
            u.uw[2] = t2;
            u.uw[3] = t4;
            const int colE = ks * 16 + hf * 8;
            s16x8 vf0 = *(const s16x8*)&VtC[ll * 64 + (colE ^ xorl)];
            s16x8 vf1 = *(const s16x8*)&VtC[(32 + ll) * 64 + (colE ^ xorl)];
            o0 = __builtin_amdgcn_mfma_f32_32x32x16_bf16(vf0, u.v, o0, 0, 0, 0);
            o1 = __builtin_amdgcn_mfma_f32_32x32x16_bf16(vf1, u.v, o1, 0, 0, 0);
        }
        // counted wait: next tile's V landed; tile t+2's V may stay in flight
        __builtin_amdgcn_sched_barrier(0);
        asm volatile("s_waitcnt vmcnt(1)" ::: "memory");
        __builtin_amdgcn_s_barrier();
        __builtin_amdgcn_sched_barrier(0);
        cur = cur + 1; if (cur >= 3) cur = 0;
    }
    lsum += __shfl_xor(lsum, 32, 64);
    const size_t bq = ((size_t)sp * 256 + (qrow0 >> 4) + (ll >> 4)) * 384;
    const int q15 = ll & 15;
#pragma unroll
    for (int r = 0; r < 16; r++) {
        const int e_a = h * 64 + CROW(r, hf);
        pof[(bq + e_a) * 16 + q15] = f2bf(o0[r]);
        pof[(bq + e_a + 32) * 16 + q15] = f2bf(o1[r]);
    }
    if (hf == 0)
        pml[((size_t)sp * Hh + h) * Nn + qrow0 + ll] = lsum;
#undef STAGE
#undef NT
}

// ---------------- kernel: merge + out-proj + residual + LayerNorm + weighted partials ----------------
// grid 256 x 512 thr (8 waves); 16 rows/block
__global__ __launch_bounds__(512) void k_oln(
    const ushort_t* __restrict__ pof, const float* __restrict__ pml,
    const ushort_t* __restrict__ wT, const float* __restrict__ bo,
    const ushort_t* __restrict__ fusedb,
    const float* __restrict__ lng, const float* __restrict__ lnb,
    const float* __restrict__ rw, float* __restrict__ part) {
    __shared__ ushort_t cx[16][384];
    __shared__ float xs[16][388];
    __shared__ float stats[16][2];
    __shared__ float dinvs[Hh][16];
    const int t = threadIdx.x;
    const int w = t >> 6, l = t & 63, l15 = l & 15, g4 = l >> 4;
    const int rb = blockIdx.x * 16;
    const int rbq = blockIdx.x;
    if (t < Hh * 16) {
        const int hh = t >> 4, qq = t & 15;
        float den = 0.0f;
#pragma unroll
        for (int s = 0; s < SPLIT; s++)
            den += pml[((size_t)s * Hh + hh) * Nn + rb + qq];
        dinvs[hh][qq] = 1.0f / den;
    }
    __syncthreads();
    for (int task = t; task < 768; task += 512) {
        const int e = task >> 1, half = task & 1;
        const int hh = e >> 6;
        float a8[8];
#pragma unroll
        for (int j = 0; j < 8; j++) a8[j] = 0.0f;
#pragma unroll
        for (int s = 0; s < SPLIT; s++) {
            s16x8 v = *(const s16x8*)&pof[(((size_t)s * 256 + rbq) * 384 + e) * 16 + half * 8];
#pragma unroll
            for (int j = 0; j < 8; j++) a8[j] += bf2f((ushort_t)v[j]);
        }
#pragma unroll
        for (int j = 0; j < 8; j++) {
            const int q = half * 8 + j;
            cx[q][e ^ ((q & 7) << 3)] = f2bf(a8[j] * dinvs[hh][q]);
        }
    }
    __syncthreads();
    const ushort_t* woT = wT + WO_OFF;
    f32x4 oA[3];
#pragma unroll
    for (int nt = 0; nt < 3; nt++) oA[nt] = (f32x4){0.f, 0.f, 0.f, 0.f};
    const int xo = (l15 & 7) << 3;
    for (int ks = 0; ks < 12; ks++) {
        s16x8 af = *(const s16x8*)&cx[l15][(ks * 32 + g4 * 8) ^ xo];
#pragma unroll
        for (int nt = 0; nt < 3; nt++) {
            s16x8 bf = *(const s16x8*)&woT[(size_t)(w * 48 + nt * 16 + l15) * 384 + ks * 32 + g4 * 8];
            oA[nt] = __builtin_amdgcn_mfma_f32_16x16x32_bf16(af, bf, oA[nt], 0, 0, 0);
        }
    }
#pragma unroll
    for (int nt = 0; nt < 3; nt++) {
        const int col = w * 48 + nt * 16 + l15;
        const float bias = bo[col];
#pragma unroll
        for (int r = 0; r < 4; r++) {
            const int row = g4 * 4 + r;
            xs[row][col] = oA[nt][r] + bias + bf2f(fusedb[(size_t)(rb + row) * 384 + col]);
        }
    }
    __syncthreads();
    {
        const int row = t >> 5, j = t & 31;
        float s1 = 0.0f, s2 = 0.0f;
        for (int i = 0; i < 12; i++) {
            const float x = xs[row][j + 32 * i];
            s1 += x;
            s2 += x * x;
        }
#pragma unroll
        for (int off = 1; off < 32; off <<= 1) {
            s1 += __shfl_xor(s1, off, 64);
            s2 += __shfl_xor(s2, off, 64);
        }
        if (j == 0) {
            const float mu = s1 * (1.0f / Ee);
            const float var = s2 * (1.0f / Ee) - mu * mu;
            stats[row][0] = mu;
            stats[row][1] = rsqrtf(var + 1e-5f);
        }
    }
    __syncthreads();
    for (int c = t; c < 384; c += 512) {
        const float gt = lng[c], bb = lnb[c];
        float acc = 0.0f;
        for (int r = 0; r < 16; r++) {
            const float xn = (xs[r][c] - stats[r][0]) * stats[r][1] * gt + bb;
            acc += xn * rw[rb + r];
        }
        part[(size_t)blockIdx.x * Ee + c] = acc;
    }
}

// ---------------- kernel: ordered partial reduce + L2 normalize (winv folded into eps) ----------------
__global__ __launch_bounds__(384) void k_final(const float* __restrict__ part,
                                               const float* __restrict__ rw,
                                               float* __restrict__ outp) {
    __shared__ float red[6], redw[6];
    const int t = threadIdx.x;
    float s = 0.0f;
    for (int b = 0; b < 256; b++) s += part[(size_t)b * Ee + t];
    float wsp = 0.0f;
    for (int i = t; i < Nn; i += 384) wsp += rw[i];
    float q2 = s * s;
#pragma unroll
    for (int off = 32; off > 0; off >>= 1) {
        q2 += __shfl_down(q2, off, 64);
        wsp += __shfl_down(wsp, off, 64);
    }
    const int wid = t >> 6, lane = t & 63;
    if (lane == 0) { red[wid] = q2; redw[wid] = wsp; }
    __syncthreads();
    float tot = 0.0f, wtot = 0.0f;
#pragma unroll
    for (int w = 0; w < 6; w++) { tot += red[w]; wtot += redw[w]; }
    outp[t] = s / (sqrtf(tot) + 1e-8f * wtot);
}

extern "C" void kernel_launch(void* const* d_in, const int* in_sizes, int n_in,
                              void* d_out, int out_size, void* d_ws, size_t ws_size,
                              hipStream_t stream) {
    const float* low  = (const float*)d_in[0];
    const float* high = (const float*)d_in[1];
    const float* rw   = (const float*)d_in[2];
    const float* lw1  = (const float*)d_in[3];
    const float* lb1  = (const float*)d_in[4];
    const float* lw2  = (const float*)d_in[5];
    const float* lb2  = (const float*)d_in[6];
    const float* hw1  = (const float*)d_in[7];
    const float* hb1  = (const float*)d_in[8];
    const float* hw2  = (const float*)d_in[9];
    const float* hb2  = (const float*)d_in[10];
    const float* lf   = (const float*)d_in[11];
    const float* wqkv = (const float*)d_in[12];
    const float* bqkv = (const float*)d_in[13];
    const float* wo   = (const float*)d_in[14];
    const float* bo   = (const float*)d_in[15];
    const float* lng  = (const float*)d_in[16];
    const float* lnb  = (const float*)d_in[17];

    float* ws = (float*)d_ws;
    const size_t NE = (size_t)Nn * Ee;
    float* pml  = ws;                      // SPLIT*Hh*Nn = 196608 f32 (lsum only)
    float* part = ws + 196608;             // 256*384 f32
    ushort_t* u16base = (ushort_t*)(ws + 294912);
    ushort_t* fusedb = u16base;
    ushort_t* vtb    = u16base + NE;
    ushort_t* qb     = u16base + 2 * NE;
    ushort_t* kb     = u16base + 3 * NE;
    ushort_t* wT     = u16base + 4 * NE;   // 737280
    ushort_t* pof    = wT + 737280;        // SPLIT*Ee*Nn

    hipLaunchKernelGGL(k_cvt, dim3(720), dim3(256), 0, stream,
                       lw1, hw1, lw2, hw2, wqkv, wo, wT);
    hipLaunchKernelGGL(k_mlp, dim3(256), dim3(256), 0, stream,
                       low, high, lf, wT, lb1, lb2, hb1, hb2, fusedb);
    hipLaunchKernelGGL(k_qkv, dim3(128, 6), dim3(128), 0, stream,
                       fusedb, wT, bqkv, qb, kb, vtb);
    hipLaunchKernelGGL(k_attn, dim3(Hh * SPLIT * 16), dim3(512), 0, stream,
                       qb, kb, vtb, pof, pml);
    hipLaunchKernelGGL(k_oln, dim3(256), dim3(512), 0, stream,
                       pof, pml, wT, bo, fusedb, lng, lnb, rw, part);
    hipLaunchKernelGGL(k_final, dim3(1), dim3(384), 0, stream, part, rw, (float*)d_out);
}

// Round 20
// 124.208 us; speedup vs baseline: 1.1791x; 1.1791x over previous
//
#include <hip/hip_runtime.h>
#include <math.h>

#define Nn 4096
#define Ee 384
#define Hh 6
#define DHh 64
#define MIDm 96
#define TEe 1152
#define SPLIT 8

typedef short s16x8 __attribute__((ext_vector_type(8)));
typedef float f32x4 __attribute__((ext_vector_type(4)));
typedef float f32x16 __attribute__((ext_vector_type(16)));
typedef unsigned short ushort_t;
typedef unsigned short ushort4_t __attribute__((ext_vector_type(4)));

#define CROW(r, hf) ((((r) & 3)) + 8 * ((r) >> 2) + 4 * (hf))

__device__ __forceinline__ float gelu_exact(float x) {
    return 0.5f * x * (1.0f + erff(x * 0.70710678118654752f));
}
__device__ __forceinline__ float sigmoidf_(float x) {
    return 1.0f / (1.0f + __expf(-x));
}
__device__ __forceinline__ ushort_t f2bf(float x) {
    unsigned int u = __float_as_uint(x);
    u = (u + 0x7FFFu + ((u >> 16) & 1u)) >> 16;
    return (ushort_t)u;
}
__device__ __forceinline__ float bf2f(ushort_t u) {
    return __uint_as_float(((unsigned int)u) << 16);
}
__device__ __forceinline__ unsigned int cvtpk(float a, float b) {
    unsigned int r;
    asm("v_cvt_pk_bf16_f32 %0, %1, %2" : "=v"(r) : "v"(a), "v"(b));
    return r;
}
// async global->LDS 16B: per-lane global src, wave-uniform LDS base + lane*16
__device__ __forceinline__ void gld16(const ushort_t* g, ushort_t* l) {
    __builtin_amdgcn_global_load_lds(
        (const __attribute__((address_space(1))) unsigned int*)g,
        (__attribute__((address_space(3))) unsigned int*)l, 16, 0, 0);
}

// weight-region offsets (ushort units)
#define W1L_OFF 0
#define W1H_OFF 36864
#define W2L_OFF 73728
#define W2H_OFF 110592
#define WQKV_OFF 147456
#define WO_OFF 589824

// ---------------- kernel: tiled transpose+convert weights to bf16 ----------------
__global__ __launch_bounds__(256) void k_cvt(
    const float* __restrict__ lw1, const float* __restrict__ hw1,
    const float* __restrict__ lw2, const float* __restrict__ hw2,
    const float* __restrict__ wqkv, const float* __restrict__ wo,
    ushort_t* __restrict__ wT) {
    __shared__ float tl[32][33];
    const int b = blockIdx.x;
    const float* src;
    int R, C, doff, ti;
    if (b < 36)       { src = lw1;  R = 384; C = 96;   doff = W1L_OFF;  ti = b; }
    else if (b < 72)  { src = hw1;  R = 384; C = 96;   doff = W1H_OFF;  ti = b - 36; }
    else if (b < 108) { src = lw2;  R = 96;  C = 384;  doff = W2L_OFF;  ti = b - 72; }
    else if (b < 144) { src = hw2;  R = 96;  C = 384;  doff = W2H_OFF;  ti = b - 108; }
    else if (b < 576) { src = wqkv; R = 384; C = 1152; doff = WQKV_OFF; ti = b - 144; }
    else              { src = wo;   R = 384; C = 384;  doff = WO_OFF;   ti = b - 576; }
    const int tcn = C >> 5;
    const int tr = ti / tcn, tc = ti % tcn;
    const int col = threadIdx.x & 31, r8 = threadIdx.x >> 5;
#pragma unroll
    for (int i = 0; i < 4; i++) {
        const int row = r8 + 8 * i;
        tl[row][col] = src[(size_t)(tr * 32 + row) * C + tc * 32 + col];
    }
    __syncthreads();
#pragma unroll
    for (int i = 0; i < 4; i++) {
        const int rowp = r8 + 8 * i;  // src-col within tile
        wT[doff + (size_t)(tc * 32 + rowp) * R + tr * 32 + col] = f2bf(tl[col][rowp]);
    }
}

// ---------------- kernel: dual channel-MLP + layer fuse (16x16x32 MFMA) ----------------
// grid 256 x 256 thr (4 waves = stream x n-half); 16 rows/block
__global__ __launch_bounds__(256) void k_mlp(
    const float* __restrict__ low, const float* __restrict__ high,
    const float* __restrict__ lf, const ushort_t* __restrict__ wT,
    const float* __restrict__ lb1, const float* __restrict__ lb2,
    const float* __restrict__ hb1, const float* __restrict__ hb2,
    ushort_t* __restrict__ fusedb) {
    __shared__ ushort_t Hs[2][16][104];
    __shared__ ushort_t Sg[2][16][384];
    const int t = threadIdx.x;
    const int w = t >> 6, l = t & 63, l15 = l & 15, g4 = l >> 4;
    const int st = w >> 1, nh = w & 1;
    const int rb = blockIdx.x * 16;
    const float* Xf = st ? high : low;
    const ushort_t* w1T = wT + (st ? W1H_OFF : W1L_OFF);
    const ushort_t* w2T = wT + (st ? W2H_OFF : W2L_OFF);
    const float* b1p = st ? hb1 : lb1;
    const float* b2p = st ? hb2 : lb2;
    // ---- GEMM1: wave (st, nh) computes cols nh*48..+48, full K=384
    {
        f32x4 hA[3];
#pragma unroll
        for (int nt = 0; nt < 3; nt++) hA[nt] = (f32x4){0.f, 0.f, 0.f, 0.f};
        for (int ks = 0; ks < 12; ks++) {
            const float* ap = &Xf[(size_t)(rb + l15) * 384 + ks * 32 + g4 * 8];
            f32x4 a0 = *(const f32x4*)ap;
            f32x4 a1 = *(const f32x4*)(ap + 4);
            union { unsigned int uw[4]; s16x8 v; } ua;
            ua.uw[0] = cvtpk(a0[0], a0[1]);
            ua.uw[1] = cvtpk(a0[2], a0[3]);
            ua.uw[2] = cvtpk(a1[0], a1[1]);
            ua.uw[3] = cvtpk(a1[2], a1[3]);
#pragma unroll
            for (int nt = 0; nt < 3; nt++) {
                s16x8 bf = *(const s16x8*)&w1T[(nh * 48 + nt * 16 + l15) * 384 + ks * 32 + g4 * 8];
                hA[nt] = __builtin_amdgcn_mfma_f32_16x16x32_bf16(ua.v, bf, hA[nt], 0, 0, 0);
            }
        }
#pragma unroll
        for (int nt = 0; nt < 3; nt++) {
            const int mc = nh * 48 + nt * 16 + l15;
            const float bb = b1p[mc];
#pragma unroll
            for (int r = 0; r < 4; r++)
                Hs[st][g4 * 4 + r][mc] = f2bf(gelu_exact(hA[nt][r] + bb));
        }
    }
    __syncthreads();
    // ---- GEMM2: wave (st, nh) covers 192 cols: 12 chains x 3 ksteps
    {
        f32x4 sA[12];
#pragma unroll
        for (int nt = 0; nt < 12; nt++) sA[nt] = (f32x4){0.f, 0.f, 0.f, 0.f};
#pragma unroll
        for (int ks = 0; ks < 3; ks++) {
            s16x8 af = *(const s16x8*)&Hs[st][l15][ks * 32 + g4 * 8];
#pragma unroll
            for (int nt = 0; nt < 12; nt++) {
                s16x8 bf = *(const s16x8*)&w2T[(nh * 192 + nt * 16 + l15) * 96 + ks * 32 + g4 * 8];
                sA[nt] = __builtin_amdgcn_mfma_f32_16x16x32_bf16(af, bf, sA[nt], 0, 0, 0);
            }
        }
#pragma unroll
        for (int nt = 0; nt < 12; nt++) {
            const float bb = b2p[nh * 192 + nt * 16 + l15];
#pragma unroll
            for (int r = 0; r < 4; r++)
                Sg[st][g4 * 4 + r][nh * 192 + nt * 16 + l15] = f2bf(sigmoidf_(sA[nt][r] + bb));
        }
    }
    __syncthreads();
    // ---- fuse epilogue
    {
        const float a0 = lf[0], a1 = lf[1];
        const float mx = fmaxf(a0, a1);
        const float e0 = __expf(a0 - mx), e1 = __expf(a1 - mx);
        const float inv = 1.0f / (e0 + e1);
        const float w0 = e0 * inv, w1v = e1 * inv;
        for (int base = t * 4; base < 16 * 384; base += 256 * 4) {
            const int row = base / 384, e0i = base % 384;
            const int gr = rb + row;
            f32x4 lo4 = *(const f32x4*)&low[(size_t)gr * 384 + e0i];
            f32x4 hi4 = *(const f32x4*)&high[(size_t)gr * 384 + e0i];
            ushort4_t s0 = *(const ushort4_t*)&Sg[0][row][e0i];
            ushort4_t s1 = *(const ushort4_t*)&Sg[1][row][e0i];
            ushort4_t fb;
#pragma unroll
            for (int i = 0; i < 4; i++)
                fb[i] = f2bf(w0 * lo4[i] * bf2f(s0[i]) + w1v * hi4[i] * bf2f(s1[i]));
            *(ushort4_t*)&fusedb[(size_t)gr * 384 + e0i] = fb;
        }
    }
}

// ---------------- kernel: qkv projection (32x32x16 MFMA, no A-staging) ----------------
// grid (128, 6) x 128 thr (2 waves); 32 rows x 192 cols per block
__global__ __launch_bounds__(128) void k_qkv(
    const ushort_t* __restrict__ fusedb, const ushort_t* __restrict__ wT,
    const float* __restrict__ bqkv,
    ushort_t* __restrict__ qb, ushort_t* __restrict__ kb, ushort_t* __restrict__ vtb) {
    __shared__ float tls[2][32][40];
    const int t = threadIdx.x;
    const int w = t >> 6, l = t & 63, ll = l & 31, hf = l >> 5;
    const int rb = blockIdx.x * 32;
    const int cb = blockIdx.y * 192 + w * 96;
    const ushort_t* wq = wT + WQKV_OFF;
    f32x16 acc[3];
#pragma unroll
    for (int nt = 0; nt < 3; nt++)
#pragma unroll
        for (int r = 0; r < 16; r++) acc[nt][r] = 0.0f;
    for (int ks = 0; ks < 24; ks++) {
        s16x8 af = *(const s16x8*)&fusedb[(size_t)(rb + ll) * 384 + ks * 16 + hf * 8];
#pragma unroll
        for (int nt = 0; nt < 3; nt++) {
            s16x8 bf = *(const s16x8*)&wq[(size_t)(cb + nt * 32 + ll) * 384 + ks * 16 + hf * 8];
            acc[nt] = __builtin_amdgcn_mfma_f32_32x32x16_bf16(af, bf, acc[nt], 0, 0, 0);
        }
    }
#pragma unroll
    for (int nt = 0; nt < 3; nt++) {
        const int nb = cb + nt * 32;
        const int which = nb / 384, wn = nb % 384;
        const int hb = wn >> 6, d0 = wn & 63;
        const float bias = bqkv[nb + ll];
        if (which == 2) {
            const int d = d0 + ll;
#pragma unroll
            for (int g2 = 0; g2 < 4; g2++) {
                ushort4_t u4;
#pragma unroll
                for (int i2 = 0; i2 < 4; i2++) u4[i2] = f2bf(acc[nt][g2 * 4 + i2] + bias);
                *(ushort4_t*)&vtb[((size_t)(hb * 64 + d)) * Nn + rb + 8 * g2 + 4 * hf] = u4;
            }
        } else {
            const float sc = (which == 0) ? 0.18033688f : 1.0f;  // 0.125*log2(e) on q
#pragma unroll
            for (int r = 0; r < 16; r++) tls[w][CROW(r, hf)][ll] = (acc[nt][r] + bias) * sc;
            ushort_t* dst = which ? kb : qb;
            const int row2 = l >> 1, sg = l & 1;
            union { ushort_t us[16]; s16x8 v[2]; } u;
#pragma unroll
            for (int j = 0; j < 16; j++) u.us[j] = f2bf(tls[w][row2][sg * 16 + j]);
            size_t base = ((size_t)hb * Nn + rb + row2) * 64 + d0 + sg * 16;
            *(s16x8*)&dst[base] = u.v[0];
            *(s16x8*)&dst[base + 8] = u.v[1];
        }
    }
}

// ---------------- kernel: flash attention, softmax-free, T4 counted-vmcnt 3-buf pipeline ----------------
// flat grid 768 (XCD-swizzled) x 512 thr (8 waves); KV tile 64; raw s_barrier, vmcnt(2)
// pof layout: [sp][q/16][e][q%16]
__global__ __launch_bounds__(512) void k_attn(
    const ushort_t* __restrict__ qb, const ushort_t* __restrict__ kb,
    const ushort_t* __restrict__ vtb, ushort_t* __restrict__ pof,
    float* __restrict__ pml) {
    __shared__ ushort_t Kt[3][4096];
    __shared__ ushort_t Vt[3][4096];
    const int t = threadIdx.x;
    const int wid8 = t >> 6, l = t & 63, ll = l & 31, hf = l >> 5;
    const int lid = blockIdx.x;
    const int xcd = lid & 7, gi = lid >> 3;
    const int pair = xcd * 6 + (gi >> 4);
    const int qt = gi & 15;
    const int h = pair % Hh, sp = pair / Hh;
    const int qrow0 = qt * 256 + wid8 * 32;
    const int srow = t >> 3;
    const int sslot = ((l & 7) ^ (l >> 3)) * 8;
    const int wch = wid8 * 512;
    const ushort_t* kbase = kb + (size_t)h * Nn * DHh;
    const ushort_t* vbase = vtb + (size_t)h * DHh * Nn;
    const int kst0 = sp * (Nn / SPLIT);
#define NT (Nn / (64 * SPLIT))
#define STAGE(B, TI) { const int ktb2 = kst0 + (TI) * 64;                                \
        gld16(kbase + (size_t)(ktb2 + srow) * DHh + sslot, &Kt[B][wch]);                 \
        gld16(vbase + (size_t)srow * Nn + ktb2 + sslot, &Vt[B][wch]); }

    s16x8 qf[4];
#pragma unroll
    for (int dc = 0; dc < 4; dc++)
        qf[dc] = *(const s16x8*)&qb[((size_t)h * Nn + qrow0 + ll) * DHh + dc * 16 + hf * 8];
    f32x16 zro;
#pragma unroll
    for (int r = 0; r < 16; r++) zro[r] = 0.0f;
    f32x16 o0 = zro, o1 = zro;
    float lsum = 0.0f;
    const int xorl = (ll & 7) << 3;

    // 2-deep DMA pipeline prologue
    STAGE(0, 0);
    STAGE(1, 1);
    asm volatile("s_waitcnt vmcnt(2)" ::: "memory");   // tile 0 landed
    __builtin_amdgcn_s_barrier();
    __builtin_amdgcn_sched_barrier(0);
    int cur = 0;
    for (int kt = 0; kt < NT; kt++) {
        int nb = cur + 2; if (nb >= 3) nb -= 3;
        if (kt + 2 < NT) STAGE(nb, kt + 2);            // keep 2 tiles in flight
        const ushort_t* KtC = Kt[cur];
        const ushort_t* VtC = Vt[cur];
        __builtin_amdgcn_s_setprio(1);
        f32x16 s0, s1;
        {
            const int colE = hf * 8;
            s16x8 kf0 = *(const s16x8*)&KtC[ll * 64 + (colE ^ xorl)];
            s16x8 kf1 = *(const s16x8*)&KtC[(32 + ll) * 64 + (colE ^ xorl)];
            s0 = __builtin_amdgcn_mfma_f32_32x32x16_bf16(kf0, qf[0], zro, 0, 0, 0);
            s1 = __builtin_amdgcn_mfma_f32_32x32x16_bf16(kf1, qf[0], zro, 0, 0, 0);
        }
#pragma unroll
        for (int dc = 1; dc < 4; dc++) {
            const int colE = dc * 16 + hf * 8;
            s16x8 kf0 = *(const s16x8*)&KtC[ll * 64 + (colE ^ xorl)];
            s16x8 kf1 = *(const s16x8*)&KtC[(32 + ll) * 64 + (colE ^ xorl)];
            s0 = __builtin_amdgcn_mfma_f32_32x32x16_bf16(kf0, qf[dc], s0, 0, 0, 0);
            s1 = __builtin_amdgcn_mfma_f32_32x32x16_bf16(kf1, qf[dc], s1, 0, 0, 0);
        }
        __builtin_amdgcn_s_setprio(0);
#pragma unroll
        for (int r = 0; r < 16; r++) { s0[r] = exp2f(s0[r]); lsum += s0[r]; }
#pragma unroll
        for (int r = 0; r < 16; r++) { s1[r] = exp2f(s1[r]); lsum += s1[r]; }
#pragma unroll
        for (int ks = 0; ks < 4; ks++) {
            const f32x16 S = (ks < 2) ? s0 : s1;
            const int b = (ks & 1) * 8;
            unsigned int t1 = cvtpk(S[b + 0], S[b + 1]);
            unsigned int t3 = cvtpk(S[b + 2], S[b + 3]);
            unsigned int t2 = cvtpk(S[b + 4], S[b + 5]);
            unsigned int t4 = cvtpk(S[b + 6], S[b + 7]);
            asm("v_permlane32_swap_b32 %0, %1" : "+v"(t1), "+v"(t2));
            asm("v_permlane32_swap_b32 %0, %1" : "+v"(t3), "+v"(t4));
            union { unsigned int uw[4]; s16x8 v; } u;
            u.uw[0] = t1;
            u.uw[1] = t3;
            u.uw[2] = t2;
            u.uw[3] = t4;
            const int colE = ks * 16 + hf * 8;
            s16x8 vf0 = *(const s16x8*)&VtC[ll * 64 + (colE ^ xorl)];
            s16x8 vf1 = *(const s16x8*)&VtC[(32 + ll) * 64 + (colE ^ xorl)];
            o0 = __builtin_amdgcn_mfma_f32_32x32x16_bf16(vf0, u.v, o0, 0, 0, 0);
            o1 = __builtin_amdgcn_mfma_f32_32x32x16_bf16(vf1, u.v, o1, 0, 0, 0);
        }
        __builtin_amdgcn_sched_barrier(0);
        asm volatile("s_waitcnt vmcnt(2)" ::: "memory");
        __builtin_amdgcn_s_barrier();
        __builtin_amdgcn_sched_barrier(0);
        cur = cur + 1; if (cur >= 3) cur = 0;
    }
    lsum += __shfl_xor(lsum, 32, 64);
    const size_t bq = ((size_t)sp * 256 + (qrow0 >> 4) + (ll >> 4)) * 384;
    const int q15 = ll & 15;
#pragma unroll
    for (int r = 0; r < 16; r++) {
        const int e_a = h * 64 + CROW(r, hf);
        pof[(bq + e_a) * 16 + q15] = f2bf(o0[r]);
        pof[(bq + e_a + 32) * 16 + q15] = f2bf(o1[r]);
    }
    if (hf == 0)
        pml[((size_t)sp * Hh + h) * Nn + qrow0 + ll] = lsum;
#undef STAGE
#undef NT
}

// ---------------- kernel: merge + out-proj + residual + LayerNorm + weighted partials ----------------
// grid 256 x 512 thr (8 waves); 16 rows/block
__global__ __launch_bounds__(512) void k_oln(
    const ushort_t* __restrict__ pof, const float* __restrict__ pml,
    const ushort_t* __restrict__ wT, const float* __restrict__ bo,
    const ushort_t* __restrict__ fusedb,
    const float* __restrict__ lng, const float* __restrict__ lnb,
    const float* __restrict__ rw, float* __restrict__ part) {
    __shared__ ushort_t cx[16][384];
    __shared__ float xs[16][388];
    __shared__ float stats[16][2];
    __shared__ float dinvs[Hh][16];
    const int t = threadIdx.x;
    const int w = t >> 6, l = t & 63, l15 = l & 15, g4 = l >> 4;
    const int rb = blockIdx.x * 16;
    const int rbq = blockIdx.x;
    if (t < Hh * 16) {
        const int hh = t >> 4, qq = t & 15;
        float den = 0.0f;
#pragma unroll
        for (int s = 0; s < SPLIT; s++)
            den += pml[((size_t)s * Hh + hh) * Nn + rb + qq];
        dinvs[hh][qq] = 1.0f / den;
    }
    __syncthreads();
    for (int task = t; task < 768; task += 512) {
        const int e = task >> 1, half = task & 1;
        const int hh = e >> 6;
        float a8[8];
#pragma unroll
        for (int j = 0; j < 8; j++) a8[j] = 0.0f;
#pragma unroll
        for (int s = 0; s < SPLIT; s++) {
            s16x8 v = *(const s16x8*)&pof[(((size_t)s * 256 + rbq) * 384 + e) * 16 + half * 8];
#pragma unroll
            for (int j = 0; j < 8; j++) a8[j] += bf2f((ushort_t)v[j]);
        }
#pragma unroll
        for (int j = 0; j < 8; j++) {
            const int q = half * 8 + j;
            cx[q][e ^ ((q & 7) << 3)] = f2bf(a8[j] * dinvs[hh][q]);
        }
    }
    __syncthreads();
    const ushort_t* woT = wT + WO_OFF;
    f32x4 oA[3];
#pragma unroll
    for (int nt = 0; nt < 3; nt++) oA[nt] = (f32x4){0.f, 0.f, 0.f, 0.f};
    const int xo = (l15 & 7) << 3;
    for (int ks = 0; ks < 12; ks++) {
        s16x8 af = *(const s16x8*)&cx[l15][(ks * 32 + g4 * 8) ^ xo];
#pragma unroll
        for (int nt = 0; nt < 3; nt++) {
            s16x8 bf = *(const s16x8*)&woT[(size_t)(w * 48 + nt * 16 + l15) * 384 + ks * 32 + g4 * 8];
            oA[nt] = __builtin_amdgcn_mfma_f32_16x16x32_bf16(af, bf, oA[nt], 0, 0, 0);
        }
    }
#pragma unroll
    for (int nt = 0; nt < 3; nt++) {
        const int col = w * 48 + nt * 16 + l15;
        const float bias = bo[col];
#pragma unroll
        for (int r = 0; r < 4; r++) {
            const int row = g4 * 4 + r;
            xs[row][col] = oA[nt][r] + bias + bf2f(fusedb[(size_t)(rb + row) * 384 + col]);
        }
    }
    __syncthreads();
    {
        const int row = t >> 5, j = t & 31;
        float s1 = 0.0f, s2 = 0.0f;
        for (int i = 0; i < 12; i++) {
            const float x = xs[row][j + 32 * i];
            s1 += x;
            s2 += x * x;
        }
#pragma unroll
        for (int off = 1; off < 32; off <<= 1) {
            s1 += __shfl_xor(s1, off, 64);
            s2 += __shfl_xor(s2, off, 64);
        }
        if (j == 0) {
            const float mu = s1 * (1.0f / Ee);
            const float var = s2 * (1.0f / Ee) - mu * mu;
            stats[row][0] = mu;
            stats[row][1] = rsqrtf(var + 1e-5f);
        }
    }
    __syncthreads();
    for (int c = t; c < 384; c += 512) {
        const float gt = lng[c], bb = lnb[c];
        float acc = 0.0f;
        for (int r = 0; r < 16; r++) {
            const float xn = (xs[r][c] - stats[r][0]) * stats[r][1] * gt + bb;
            acc += xn * rw[rb + r];
        }
        part[(size_t)blockIdx.x * Ee + c] = acc;
    }
}

// ---------------- kernel: ordered partial reduce + L2 normalize (winv folded into eps) ----------------
__global__ __launch_bounds__(384) void k_final(const float* __restrict__ part,
                                               const float* __restrict__ rw,
                                               float* __restrict__ outp) {
    __shared__ float red[6], redw[6];
    const int t = threadIdx.x;
    float s = 0.0f;
    for (int b = 0; b < 256; b++) s += part[(size_t)b * Ee + t];
    float wsp = 0.0f;
    for (int i = t; i < Nn; i += 384) wsp += rw[i];
    float q2 = s * s;
#pragma unroll
    for (int off = 32; off > 0; off >>= 1) {
        q2 += __shfl_down(q2, off, 64);
        wsp += __shfl_down(wsp, off, 64);
    }
    const int wid = t >> 6, lane = t & 63;
    if (lane == 0) { red[wid] = q2; redw[wid] = wsp; }
    __syncthreads();
    float tot = 0.0f, wtot = 0.0f;
#pragma unroll
    for (int w = 0; w < 6; w++) { tot += red[w]; wtot += redw[w]; }
    outp[t] = s / (sqrtf(tot) + 1e-8f * wtot);
}

extern "C" void kernel_launch(void* const* d_in, const int* in_sizes, int n_in,
                              void* d_out, int out_size, void* d_ws, size_t ws_size,
                              hipStream_t stream) {
    const float* low  = (const float*)d_in[0];
    const float* high = (const float*)d_in[1];
    const float* rw   = (const float*)d_in[2];
    const float* lw1  = (const float*)d_in[3];
    const float* lb1  = (const float*)d_in[4];
    const float* lw2  = (const float*)d_in[5];
    const float* lb2  = (const float*)d_in[6];
    const float* hw1  = (const float*)d_in[7];
    const float* hb1  = (const float*)d_in[8];
    const float* hw2  = (const float*)d_in[9];
    const float* hb2  = (const float*)d_in[10];
    const float* lf   = (const float*)d_in[11];
    const float* wqkv = (const float*)d_in[12];
    const float* bqkv = (const float*)d_in[13];
    const float* wo   = (const float*)d_in[14];
    const float* bo   = (const float*)d_in[15];
    const float* lng  = (const float*)d_in[16];
    const float* lnb  = (const float*)d_in[17];

    float* ws = (float*)d_ws;
    const size_t NE = (size_t)Nn * Ee;
    float* pml  = ws;                      // SPLIT*Hh*Nn = 196608 f32 (lsum only)
    float* part = ws + 196608;             // 256*384 f32
    ushort_t* u16base = (ushort_t*)(ws + 294912);
    ushort_t* fusedb = u16base;
    ushort_t* vtb    = u16base + NE;
    ushort_t* qb     = u16base + 2 * NE;
    ushort_t* kb     = u16base + 3 * NE;
    ushort_t* wT     = u16base + 4 * NE;   // 737280
    ushort_t* pof    = wT + 737280;        // SPLIT*Ee*Nn

    hipLaunchKernelGGL(k_cvt, dim3(720), dim3(256), 0, stream,
                       lw1, hw1, lw2, hw2, wqkv, wo, wT);
    hipLaunchKernelGGL(k_mlp, dim3(256), dim3(256), 0, stream,
                       low, high, lf, wT, lb1, lb2, hb1, hb2, fusedb);
    hipLaunchKernelGGL(k_qkv, dim3(128, 6), dim3(128), 0, stream,
                       fusedb, wT, bqkv, qb, kb, vtb);
    hipLaunchKernelGGL(k_attn, dim3(Hh * SPLIT * 16), dim3(512), 0, stream,
                       qb, kb, vtb, pof, pml);
    hipLaunchKernelGGL(k_oln, dim3(256), dim3(512), 0, stream,
                       pof, pml, wT, bo, fusedb, lng, lnb, rw, part);
    hipLaunchKernelGGL(k_final, dim3(1), dim3(384), 0, stream, part, rw, (float*)d_out);
}